// Round 5
// baseline (51.563 us; speedup 1.0000x reference)
//
#include <hip/hip_runtime.h>

#define EPSF 1e-7f

// ---- DPP cross-lane helpers (VALU pipe, no DS) ----
#define DPPF0(x, ctrl) \
    __int_as_float(__builtin_amdgcn_update_dpp(0, __float_as_int(x), ctrl, 0xF, 0xF, false))

__device__ __forceinline__ float f_rcp(float x) { return __builtin_amdgcn_rcpf(x); }
__device__ __forceinline__ float wave_shr1_f(float x) { return DPPF0(x, 0x138); }

__device__ __forceinline__ float wave_max64(float x) {
    x = fmaxf(x, DPPF0(x, 0x111));   // row_shr:1
    x = fmaxf(x, DPPF0(x, 0x112));   // row_shr:2
    x = fmaxf(x, DPPF0(x, 0x114));   // row_shr:4
    x = fmaxf(x, DPPF0(x, 0x118));   // row_shr:8
    x = fmaxf(x, DPPF0(x, 0x142));   // row_bcast:15
    x = fmaxf(x, DPPF0(x, 0x143));   // row_bcast:31
    return __int_as_float(__builtin_amdgcn_readlane(__float_as_int(x), 63));
}

#define SB0() __builtin_amdgcn_sched_barrier(0)
#define WAITV(N) do { asm volatile("s_waitcnt vmcnt(" #N ")" ::: "memory"); SB0(); } while (0)

// stage 8 rows (4 KB, contiguous) into an LDS buffer: 4 coalesced
// global_load_lds width-16 (each lane writes 16 B at lbuf + lane*16).
__device__ __forceinline__ void stage8(const float* gsrc, float* lbuf, int lane) {
    const char* g = (const char*)gsrc + lane * 16;
    __builtin_amdgcn_global_load_lds((const void*)(g),        (void*)(lbuf),       16, 0, 0);
    __builtin_amdgcn_global_load_lds((const void*)(g + 1024), (void*)(lbuf + 256), 16, 0, 0);
    __builtin_amdgcn_global_load_lds((const void*)(g + 2048), (void*)(lbuf + 512), 16, 0, 0);
    __builtin_amdgcn_global_load_lds((const void*)(g + 3072), (void*)(lbuf + 768), 16, 0, 0);
}

// ---- one CTC step (identical math to the verified round-3/4 kernels) ----
#define STEP(PB_, P1_, P3_) do { \
    const float pbe = (PB_) + EPSF; \
    const float rpb = f_rcp(pbe); \
    const float q1  = ((P1_) + EPSF) * rpb; \
    const float q3  = ((P3_) + EPSF) * rpb; \
    const float n3  = wave_shr1_f(u3); \
    const float t1  = fmaf(m1, n3, u0 + u1); \
    const float t3  = fmaf(m3, u1, u2 + u3); \
    u4 = u4 + u3; \
    u3 = t3 * q3; \
    u2 = u2 + u1; \
    u1 = t1 * q1; \
    u0 = u0 + n3; \
    O += __logf(pbe); \
} while (0)

#define APPLY() do { \
    const float rm_ = f_rcp(m_carry); \
    u0 *= rm_; u1 *= rm_; u2 *= rm_; u3 *= rm_; u4 *= rm_; \
    O += __logf(m_carry); \
} while (0)

#define SNAP() do { \
    m_carry = wave_max64(fmaxf(fmaxf(u0, u1), fmaxf(u2, fmaxf(u3, u4)))); \
} while (0)

// load all 24 values of a window first (hoisted ds_reads), then 8 steps
#define LDK(k) \
    const float pb##k = R[k][127]; \
    const float pA##k = R[k][c1]; \
    const float pB##k = R[k][c3];

#define CONS8(Q) do { \
    const float (*R)[128] = lds[Q]; \
    LDK(0) LDK(1) LDK(2) LDK(3) LDK(4) LDK(5) LDK(6) LDK(7) \
    STEP(pb0, pA0, pB0); STEP(pb1, pA1, pB1); APPLY(); \
    STEP(pb2, pA2, pB2); STEP(pb3, pA3, pB3); STEP(pb4, pA4, pB4); \
    STEP(pb5, pA5, pB5); STEP(pb6, pA6, pB6); STEP(pb7, pA7, pB7); \
    SNAP(); \
} while (0)

// Specialized T=512, C=128, U=128. One wave per batch row; lane l owns states
// 4l..4l+3 (+256 on lane 63). Rows streamed HBM->LDS in 8-row windows,
// triple-buffered, counted vmcnt; per-step values via ds_read.
__global__ __launch_bounds__(64, 1) void ctc_lds512(
        const int* __restrict__ y_true, const float* __restrict__ y_pred,
        float* __restrict__ out) {
    const int b    = blockIdx.x;
    const int lane = threadIdx.x;
    const float* __restrict__ yp = y_pred + (size_t)b * (512 * 128);

    __shared__ float lds[4][8][128];   // 3 rotating windows + tail buffer

    const int2 lc = ((const int2*)(y_true + (size_t)b * 128))[lane];
    const int c1 = lc.x, c3 = lc.y;
    const int cp = __builtin_amdgcn_update_dpp(0, c3, 0x138, 0xF, 0xF, false);
    const float m1 = (lane > 0 && c1 != cp) ? 1.f : 0.f;
    const float m3 = (c3 != c1) ? 1.f : 0.f;

    float u0, u1, u2 = 0.f, u3 = 0.f, u4 = 0.f;
    {
        const float pvb = yp[127];     // blank prob at t=0
        const float pv1 = yp[c1];
        u0 = (lane == 0) ? pvb + EPSF : 0.f;
        u1 = (lane == 0) ? pv1 + EPSF : 0.f;
    }
    float O = 0.f, m_carry = 1.0f;

    WAITV(0);   // all init loads retired; explicit vmcnt counting starts at 0

    // prologue: stage W0 (rows 1..8), W1 (9..16), W2 (17..24)
    stage8(yp + 1 * 128,  &lds[0][0][0], lane);
    stage8(yp + 9 * 128,  &lds[1][0][0], lane);
    stage8(yp + 17 * 128, &lds[2][0][0], lane);

    const float* gp = yp + 25 * 128;   // start of W3

    // windows 0..59 (rows 1..480): steady state, 12 staging loads in flight
#pragma unroll 1
    for (int j = 0; j < 20; ++j) {
        WAITV(8);  CONS8(0);  stage8(gp, &lds[0][0][0], lane);  gp += 1024;
        WAITV(8);  CONS8(1);  stage8(gp, &lds[1][0][0], lane);  gp += 1024;
        WAITV(8);  CONS8(2);  stage8(gp, &lds[2][0][0], lane);  gp += 1024;
    }
    // w=60 (rows 481..488); stage tail rows 504..511 into buffer 3
    WAITV(8);  CONS8(0);  stage8(yp + 504 * 128, &lds[3][0][0], lane);
    // w=61 (rows 489..496)
    WAITV(8);  CONS8(1);
    // w=62 (rows 497..504)
    WAITV(4);  CONS8(2);
    // tail: rows 505..511 from buffer 3 (indices 1..7)
    WAITV(0);
    {
        const float (*R)[128] = lds[3];
        STEP(R[1][127], R[1][c1], R[1][c3]);
        STEP(R[2][127], R[2][c1], R[2][c3]);
        APPLY();
        STEP(R[3][127], R[3][c1], R[3][c3]);
        STEP(R[4][127], R[4][c1], R[4][c3]);
        STEP(R[5][127], R[5][c1], R[5][c3]);
        STEP(R[6][127], R[6][c1], R[6][c3]);
        STEP(R[7][127], R[7][c1], R[7][c3]);
    }

    if (lane == 63) out[b] = -(O + __logf(u3 + u4));
}

// ---- generic fallback (verified round-3 kernel) for other shapes ----
__global__ __launch_bounds__(64, 1) void ctc_scan_generic(
        const int* __restrict__ y_true, const float* __restrict__ y_pred,
        float* __restrict__ out, int T, int C, int U) {
    const int b    = blockIdx.x;
    const int lane = threadIdx.x;
    const int blank = C - 1;
    const float* __restrict__ yp = y_pred + (size_t)b * T * C;

    const int2 lc = ((const int2*)(y_true + (size_t)b * U))[lane];
    const int c1 = lc.x, c3 = lc.y;
    const int cp = __builtin_amdgcn_update_dpp(0, c3, 0x138, 0xF, 0xF, false);
    const float m1 = (lane > 0 && c1 != cp) ? 1.f : 0.f;
    const float m3 = (c3 != c1) ? 1.f : 0.f;

    float u0, u1, u2 = 0.f, u3 = 0.f, u4 = 0.f;
    u0 = (lane == 0) ? yp[blank] + EPSF : 0.f;
    u1 = (lane == 0) ? yp[c1] + EPSF : 0.f;
    float O = 0.f, m_carry = 1.0f;
    int kren = 0;

    for (int t = 1; t < T; ++t) {
        const float* row = yp + (size_t)t * C;
        STEP(row[blank], row[c1], row[c3]);
        if (++kren == 8) { SNAP(); APPLY(); kren = 0; }
    }
    if (lane == 63) out[b] = -(O + __logf(u3 + u4));
}

extern "C" void kernel_launch(void* const* d_in, const int* in_sizes, int n_in,
                              void* d_out, int out_size, void* d_ws, size_t ws_size,
                              hipStream_t stream) {
    const int*   y_true = (const int*)d_in[0];
    const float* y_pred = (const float*)d_in[1];
    float*       out    = (float*)d_out;

    const int B = out_size;                 // 256
    const int U = in_sizes[0] / B;          // 128
    const int C = 128;                      // classes incl. blank
    const int T = in_sizes[1] / (B * C);    // 512

    if (T == 512 && C == 128 && U == 128) {
        ctc_lds512<<<B, 64, 0, stream>>>(y_true, y_pred, out);
    } else {
        ctc_scan_generic<<<B, 64, 0, stream>>>(y_true, y_pred, out, T, C, U);
    }
}